// Round 1
// baseline (404.066 us; speedup 1.0000x reference)
//
#include <hip/hip_runtime.h>
#include <stdint.h>

// RPN RoI proposal: per-batch top-2000 (exact lax.top_k order) -> decode ->
// greedy NMS (IoU>0.7, early-exit at 300 kept) -> first 300 kept, clipped.
//
// One block per batch image. 1024 threads.
// Phase 1: 3-pass radix select on sign-flipped f32 bits (exact pivot).
// Phase 2: gather >pivot + smallest-index ties; bitonic sort 2048 u64 keys.
// Phase 3: decode 2000 boxes into LDS.
// Phase 4: sequential greedy NMS with LDS bitmask, parallel suppression,
//          early exit once 300 boxes kept (keep flags are monotone, so the
//          first 300 kept are final as soon as they are discovered).
// Phase 5: write [300,4] clipped, zero-padded.

#define PRE 2000
#define POST 300
#define IOU_THR 0.7f
#define EPSV 1e-8f
#define SORTN 2048
#define TIECAP 64
#define NT 1024

__device__ __forceinline__ uint32_t flip_f32(uint32_t b) {
    // monotone map: float total order -> unsigned total order
    return b ^ ((uint32_t)((int32_t)b >> 31) | 0x80000000u);
}

__global__ __launch_bounds__(NT) void roibbox_kernel(
    const float4* __restrict__ deltas,   // [B*N] (dy,dx,dh,dw)
    const float*  __restrict__ labels,   // [B*N]
    const float4* __restrict__ anchors,  // [N]   (y1,x1,y2,x2)
    float4*       __restrict__ out,      // [B*POST]
    int N)
{
    const int b   = blockIdx.x;
    const int tid = threadIdx.x;

    __shared__ union SU {
        uint32_t hist[2048];                          // phase 1 only
        struct { float4 box[PRE]; float area[PRE]; } s;  // phase 3+
    } u;
    __shared__ uint64_t pairs[SORTN];   // (flipped_bits<<32) | ~idx
    __shared__ uint32_t tieidx[TIECAP];
    __shared__ uint32_t mask[63];       // 2016-bit suppression mask
    __shared__ uint32_t kept[POST];
    __shared__ int sh_bsel, sh_target, sh_cgt, sh_ctie;

    const float* score = labels + (size_t)b * N;

    // ---------------- Phase 1: radix select pivot (2000th largest) --------
    int target = PRE;
    uint32_t prefix = 0;
#pragma unroll
    for (int pass = 0; pass < 3; ++pass) {
        const int      shift = (pass == 0) ? 21 : (pass == 1) ? 10 : 0;
        const uint32_t nb    = (pass == 2) ? 1024u : 2048u;
        const uint32_t pm    = (pass == 0) ? 0u
                              : (pass == 1) ? 0xFFE00000u : 0xFFFFFC00u;

        for (int i = tid; i < (int)nb; i += NT) u.hist[i] = 0u;
        __syncthreads();
        for (int n = tid; n < N; n += NT) {
            uint32_t ub = flip_f32(__float_as_uint(score[n]));
            if ((ub & pm) == prefix)
                atomicAdd(&u.hist[(ub >> shift) & (nb - 1u)], 1u);
        }
        __syncthreads();
        if (tid == 0) {
            int acc = 0, bsel = 0;
            for (int bb = (int)nb - 1; bb >= 0; --bb) {
                int c = (int)u.hist[bb];
                if (acc + c >= target) { bsel = bb; break; }
                acc += c;
            }
            sh_bsel = bsel;
            sh_target = target - acc;   // still needed within selected bin
        }
        __syncthreads();
        prefix |= ((uint32_t)sh_bsel << shift);
        target = sh_target;
        __syncthreads();                // hist about to be reused/overlaid
    }
    const uint32_t pivot = prefix;      // exact 2000th-largest flipped value

    // ---------------- Phase 2: gather + bitonic sort -----------------------
    if (tid == 0) { sh_cgt = 0; sh_ctie = 0; }
    __syncthreads();
    for (int n = tid; n < N; n += NT) {
        uint32_t ub = flip_f32(__float_as_uint(score[n]));
        if (ub > pivot) {
            int p = atomicAdd(&sh_cgt, 1);           // < 2000 by construction
            pairs[p] = ((uint64_t)ub << 32) | (uint32_t)(~(uint32_t)n);
        } else if (ub == pivot) {
            int t = atomicAdd(&sh_ctie, 1);
            if (t < TIECAP) tieidx[t] = (uint32_t)n; // ties rare (iid floats)
        }
    }
    __syncthreads();
    const int cgt   = sh_cgt;
    const int nties = min(sh_ctie, min(TIECAP, SORTN - cgt));
    for (int t = tid; t < nties; t += NT)
        pairs[cgt + t] = ((uint64_t)pivot << 32) | (uint32_t)(~tieidx[t]);
    for (int p = cgt + nties + tid; p < SORTN; p += NT)
        pairs[p] = 0ull;                // pad: real keys all have top bit set
    __syncthreads();

    // descending bitonic sort of SORTN u64 keys, 1024 threads = 1024 pairs
    for (int k = 2; k <= SORTN; k <<= 1) {
        for (int j = k >> 1; j > 0; j >>= 1) {
            int i = 2 * tid - (tid & (j - 1));  // index with j-bit clear
            int l = i | j;
            uint64_t a = pairs[i], c = pairs[l];
            bool up = ((i & k) == 0);
            bool sw = up ? (a < c) : (a > c);   // descending overall
            if (sw) { pairs[i] = c; pairs[l] = a; }
            __syncthreads();
        }
    }

    // ---------------- Phase 3: decode top-2000 boxes into LDS -------------
    const float4* dl = deltas + (size_t)b * N;
    for (int r = tid; r < PRE; r += NT) {
        uint32_t idx = ~(uint32_t)(pairs[r] & 0xFFFFFFFFull);
        float4 bx = make_float4(0.f, 0.f, 0.f, 0.f);
        float  ar = 0.f;
        if (idx < (uint32_t)N) {        // pad guard (never hit in practice)
            float4 d  = dl[idx];
            float4 an = anchors[idx];
            float ah  = an.z - an.x;
            float aw  = an.w - an.y;
            float acy = an.x + 0.5f * ah;
            float acx = an.y + 0.5f * aw;
            float h   = expf(d.z) * ah;
            float w   = expf(d.w) * aw;
            float cy  = d.x * ah + acy;
            float cx  = d.y * aw + acx;
            float y1  = cy - 0.5f * h;
            float x1  = cx - 0.5f * w;
            bx = make_float4(y1, x1, y1 + h, x1 + w);
            ar = fmaxf(bx.z - bx.x, 0.f) * fmaxf(bx.w - bx.y, 0.f);
        }
        u.s.box[r]  = bx;
        u.s.area[r] = ar;
    }
    for (int i = tid; i < 63; i += NT) mask[i] = 0u;
    __syncthreads();

    // ---------------- Phase 4: greedy NMS with early exit -----------------
    int kc = 0;
    int i  = 0;
    while (i < PRE) {
        // skip suppressed boxes (uniform: all threads read same LDS words)
        while (i < PRE && ((mask[i >> 5] >> (i & 31)) & 1u)) ++i;
        if (i >= PRE) break;
        if (tid == 0) kept[kc] = (uint32_t)i;
        ++kc;
        if (kc >= POST) break;          // first 300 kept are final
        float4 bi = u.s.box[i];         // LDS broadcast
        float  ai = u.s.area[i];
        for (int j = i + 1 + tid; j < PRE; j += NT) {
            float4 bj = u.s.box[j];
            float yy1 = fmaxf(bi.x, bj.x);
            float xx1 = fmaxf(bi.y, bj.y);
            float yy2 = fminf(bi.z, bj.z);
            float xx2 = fminf(bi.w, bj.w);
            float inter = fmaxf(yy2 - yy1, 0.f) * fmaxf(xx2 - xx1, 0.f);
            float iou = inter / (ai + u.s.area[j] - inter + EPSV);
            if (iou > IOU_THR) atomicOr(&mask[j >> 5], 1u << (j & 31));
        }
        ++i;
        __syncthreads();
    }
    __syncthreads();

    // ---------------- Phase 5: write clipped output ------------------------
    float4* ob = out + (size_t)b * POST;
    for (int r = tid; r < POST; r += NT) {
        float4 o = make_float4(0.f, 0.f, 0.f, 0.f);
        if (r < kc) {
            float4 bx = u.s.box[kept[r]];
            o.x = fminf(fmaxf(bx.x, 0.f), 1.f);
            o.y = fminf(fmaxf(bx.y, 0.f), 1.f);
            o.z = fminf(fmaxf(bx.z, 0.f), 1.f);
            o.w = fminf(fmaxf(bx.w, 0.f), 1.f);
        }
        ob[r] = o;
    }
}

extern "C" void kernel_launch(void* const* d_in, const int* in_sizes, int n_in,
                              void* d_out, int out_size, void* d_ws, size_t ws_size,
                              hipStream_t stream) {
    const float4* deltas  = (const float4*)d_in[0];
    const float*  labels  = (const float*)d_in[1];
    const float4* anchors = (const float4*)d_in[2];
    float4*       outp    = (float4*)d_out;
    const int N = in_sizes[2] / 4;      // 90000
    const int B = in_sizes[1] / N;      // 64
    roibbox_kernel<<<B, NT, 0, stream>>>(deltas, labels, anchors, outp, N);
}

// Round 2
// 243.336 us; speedup vs baseline: 1.6605x; 1.6605x over previous
//
#include <hip/hip_runtime.h>
#include <stdint.h>

// RPN RoI proposal: per-batch exact top-2000 (lax.top_k order) -> decode ->
// greedy NMS (IoU>0.7, early-exit at 300 kept) -> first 300 kept, clipped.
//
// One block per batch image, 1024 threads.
// Phase 1: value-uniform 2048-bin histogram (scores ~U[0,1) spread evenly ->
//          no LDS same-address atomic contention), float4 loads.
// Phase 1b: parallel suffix scan over bins -> selected bin + in-bin rank
//          (replaces R1's serial thread-0 bin scans).
// Phase 2: single gather scan: bins>bsel -> pairs; bin==bsel -> candidates.
// Phase 2b: exact pivot from <=512 candidates via O(nc^2) rank on exact
//          flipped f32 bits (identical result to full bit-radix select).
// Phase 3: bitonic sort 2048 u64 keys (flipped_bits<<32 | ~idx) descending
//          -> exact lax.top_k order incl. ascending-index tie-break.
// Phase 4: decode boxes into LDS.
// Phase 5: greedy NMS with LDS bitmask; keep flags are monotone so the
//          first 300 kept are final at discovery -> early exit.
// Phase 6: write clipped [300,4], zero-padded.

#define PRE 2000
#define POST 300
#define IOU_THR 0.7f
#define EPSV 1e-8f
#define SORTN 2048
#define NBINS 2048
#define CANDCAP 512
#define NT 1024

__device__ __forceinline__ uint32_t flip_f32(uint32_t b) {
    // monotone map: float total order -> unsigned total order
    return b ^ ((uint32_t)((int32_t)b >> 31) | 0x80000000u);
}

__device__ __forceinline__ int bin_of(float s) {
    // monotone (non-injective) bucketing; uniform for U[0,1) scores
    int bn = (int)(s * 2048.0f);
    return min(max(bn, 0), NBINS - 1);
}

__global__ __launch_bounds__(NT) void roibbox_kernel(
    const float4* __restrict__ deltas,   // [B*N] (dy,dx,dh,dw)
    const float*  __restrict__ labels,   // [B*N]
    const float4* __restrict__ anchors,  // [N]   (y1,x1,y2,x2)
    float4*       __restrict__ out,      // [B*POST]
    int N)
{
    const int b   = blockIdx.x;
    const int tid = threadIdx.x;

    __shared__ union SU {
        uint32_t hist[NBINS];                            // phases 1-1b
        struct { float4 box[PRE]; float area[PRE]; } s;  // phases 4+
    } u;
    __shared__ uint64_t pairs[SORTN];    // (flipped_bits<<32) | ~idx
    __shared__ uint64_t cand[CANDCAP];   // selected-bin candidates
    __shared__ uint32_t mask[63];        // 2016-bit suppression mask
    __shared__ uint32_t kept[POST];
    __shared__ int sh_bsel, sh_tprime, sh_cnt, sh_nc;
    __shared__ uint32_t sh_pivot;

    const float*  score  = labels + (size_t)b * N;
    const float4* score4 = (const float4*)score;   // N%4==0, 16B aligned
    const int N4 = N >> 2;

    // ---- Phase 1: uniform-bin histogram ----
    for (int i = tid; i < NBINS; i += NT) u.hist[i] = 0u;
    if (tid == 0) { sh_cnt = 0; sh_nc = 0; }
    __syncthreads();
    for (int n = tid; n < N4; n += NT) {
        float4 v = score4[n];
        atomicAdd(&u.hist[bin_of(v.x)], 1u);
        atomicAdd(&u.hist[bin_of(v.y)], 1u);
        atomicAdd(&u.hist[bin_of(v.z)], 1u);
        atomicAdd(&u.hist[bin_of(v.w)], 1u);
    }
    __syncthreads();

    // ---- Phase 1b: suffix scan; hist[i] becomes S(i)=#{bin >= i} ----
    for (int off = 1; off < NBINS; off <<= 1) {
        uint32_t v0 = (tid + off        < NBINS) ? u.hist[tid + off]        : 0u;
        uint32_t v1 = (tid + 1024 + off < NBINS) ? u.hist[tid + 1024 + off] : 0u;
        __syncthreads();
        u.hist[tid]        += v0;
        u.hist[tid + 1024] += v1;
        __syncthreads();
    }
#pragma unroll
    for (int h = 0; h < 2; ++h) {
        int i = tid + h * 1024;
        uint32_t Si    = u.hist[i];
        uint32_t Snext = (i < NBINS - 1) ? u.hist[i + 1] : 0u;
        if (Si >= (uint32_t)PRE && Snext < (uint32_t)PRE) {
            sh_bsel   = i;                 // largest bin with S(bin) >= PRE
            sh_tprime = PRE - (int)Snext;  // rank still needed inside bin
        }
    }
    __syncthreads();
    const int bsel   = sh_bsel;
    const int tprime = sh_tprime;

    // ---- Phase 2: gather scan ----
    for (int n = tid; n < N4; n += NT) {
        float4 v = score4[n];
        float sv[4] = {v.x, v.y, v.z, v.w};
#pragma unroll
        for (int c = 0; c < 4; ++c) {
            int idx = 4 * n + c;
            int bn  = bin_of(sv[c]);
            if (bn >= bsel) {
                uint32_t ub  = flip_f32(__float_as_uint(sv[c]));
                uint64_t key = ((uint64_t)ub << 32) | (uint32_t)(~(uint32_t)idx);
                if (bn > bsel) {
                    int p = atomicAdd(&sh_cnt, 1);   // total = S(bsel+1) < PRE
                    pairs[p] = key;
                } else {
                    int t = atomicAdd(&sh_nc, 1);
                    if (t < CANDCAP) cand[t] = key;
                }
            }
        }
    }
    __syncthreads();

    // ---- Phase 2b: exact pivot among candidates ----
    const int nc = min(sh_nc, CANDCAP);
    for (int i = tid; i < nc; i += NT) {
        uint32_t vi = (uint32_t)(cand[i] >> 32);
        int g = 0, e = 0;
        for (int j = 0; j < nc; ++j) {
            uint32_t vj = (uint32_t)(cand[j] >> 32);
            g += (vj > vi);
            e += (vj == vi);
        }
        if (g < tprime && g + e >= tprime) sh_pivot = vi;  // unique value
    }
    __syncthreads();
    const uint32_t pivot = sh_pivot;
    for (int i = tid; i < nc; i += NT) {
        uint32_t vi = (uint32_t)(cand[i] >> 32);
        if (vi >= pivot) {               // ties included; sort orders by idx
            int p = atomicAdd(&sh_cnt, 1);
            if (p < SORTN) pairs[p] = cand[i];
        }
    }
    __syncthreads();
    const int total = min(sh_cnt, SORTN);   // >= PRE by construction
    for (int p = total + tid; p < SORTN; p += NT)
        pairs[p] = 0ull;                    // pad sorts below all real keys
    __syncthreads();

    // ---- Phase 3: descending bitonic sort of 2048 u64 keys ----
    for (int k = 2; k <= SORTN; k <<= 1) {
        for (int j = k >> 1; j > 0; j >>= 1) {
            int i = 2 * tid - (tid & (j - 1));
            int l = i | j;
            uint64_t a = pairs[i], c = pairs[l];
            bool up = ((i & k) == 0);
            bool sw = up ? (a < c) : (a > c);
            if (sw) { pairs[i] = c; pairs[l] = a; }
            __syncthreads();
        }
    }

    // ---- Phase 4: decode top-2000 boxes into LDS ----
    const float4* dl = deltas + (size_t)b * N;
    for (int r = tid; r < PRE; r += NT) {
        uint32_t idx = ~(uint32_t)(pairs[r] & 0xFFFFFFFFull);
        float4 bx = make_float4(0.f, 0.f, 0.f, 0.f);
        float  ar = 0.f;
        if (idx < (uint32_t)N) {
            float4 d  = dl[idx];
            float4 an = anchors[idx];
            float ah  = an.z - an.x;
            float aw  = an.w - an.y;
            float acy = an.x + 0.5f * ah;
            float acx = an.y + 0.5f * aw;
            float h   = expf(d.z) * ah;
            float w   = expf(d.w) * aw;
            float cy  = d.x * ah + acy;
            float cx  = d.y * aw + acx;
            float y1  = cy - 0.5f * h;
            float x1  = cx - 0.5f * w;
            bx = make_float4(y1, x1, y1 + h, x1 + w);
            ar = fmaxf(bx.z - bx.x, 0.f) * fmaxf(bx.w - bx.y, 0.f);
        }
        u.s.box[r]  = bx;
        u.s.area[r] = ar;
    }
    for (int i = tid; i < 63; i += NT) mask[i] = 0u;
    __syncthreads();

    // ---- Phase 5: greedy NMS, early exit at 300 kept ----
    int kc = 0;
    int i  = 0;
    while (i < PRE) {
        while (i < PRE && ((mask[i >> 5] >> (i & 31)) & 1u)) ++i;
        if (i >= PRE) break;
        if (tid == 0) kept[kc] = (uint32_t)i;
        ++kc;
        if (kc >= POST) break;          // keep flags monotone: final
        float4 bi = u.s.box[i];
        float  ai = u.s.area[i];
        for (int j = i + 1 + tid; j < PRE; j += NT) {
            float4 bj = u.s.box[j];
            float yy1 = fmaxf(bi.x, bj.x);
            float xx1 = fmaxf(bi.y, bj.y);
            float yy2 = fminf(bi.z, bj.z);
            float xx2 = fminf(bi.w, bj.w);
            float inter = fmaxf(yy2 - yy1, 0.f) * fmaxf(xx2 - xx1, 0.f);
            float iou = inter / (ai + u.s.area[j] - inter + EPSV);
            if (iou > IOU_THR) atomicOr(&mask[j >> 5], 1u << (j & 31));
        }
        ++i;
        __syncthreads();
    }
    __syncthreads();

    // ---- Phase 6: write clipped output ----
    float4* ob = out + (size_t)b * POST;
    for (int r = tid; r < POST; r += NT) {
        float4 o = make_float4(0.f, 0.f, 0.f, 0.f);
        if (r < kc) {
            float4 bx = u.s.box[kept[r]];
            o.x = fminf(fmaxf(bx.x, 0.f), 1.f);
            o.y = fminf(fmaxf(bx.y, 0.f), 1.f);
            o.z = fminf(fmaxf(bx.z, 0.f), 1.f);
            o.w = fminf(fmaxf(bx.w, 0.f), 1.f);
        }
        ob[r] = o;
    }
}

extern "C" void kernel_launch(void* const* d_in, const int* in_sizes, int n_in,
                              void* d_out, int out_size, void* d_ws, size_t ws_size,
                              hipStream_t stream) {
    const float4* deltas  = (const float4*)d_in[0];
    const float*  labels  = (const float*)d_in[1];
    const float4* anchors = (const float4*)d_in[2];
    float4*       outp    = (float4*)d_out;
    const int N = in_sizes[2] / 4;      // 90000
    const int B = in_sizes[1] / N;      // 64
    roibbox_kernel<<<B, NT, 0, stream>>>(deltas, labels, anchors, outp, N);
}

// Round 3
// 243.100 us; speedup vs baseline: 1.6621x; 1.0010x over previous
//
#include <hip/hip_runtime.h>
#include <stdint.h>

// RPN RoI proposal: per-batch exact top-2000 (lax.top_k order) -> decode ->
// greedy NMS (IoU>0.7) -> first 300 kept, clipped.
//
// One block per batch image, 1024 threads.
// Phase 1 : value-uniform 2048-bin histogram (float4 loads, no contention).
// Phase 1b: parallel suffix scan over bins -> selected bin + in-bin rank.
// Phase 2 : gather scan: bins>bsel -> pairs; bin==bsel -> candidates.
// Phase 2b: exact pivot among <=512 candidates (O(nc^2), exact f32 bits).
// Phase 3 : bitonic sort 2048 u64 keys (flipped_bits<<32 | ~idx) desc
//           -> exact lax.top_k order incl. ascending-index tie-break.
// Phase 4 : decode boxes into LDS.
// Phase 5a: 512x512 suppression bitmask tile (parallel, word-per-thread).
// Phase 5b: single-wave sequential reduce over tile rows (no barriers);
//           keep flags are monotone -> first 300 kept final at discovery.
// Phase 5c: fallback (kc<300 after 512 rows; not taken on this data):
//           suppress j>=512 vs kept set, continue barrier-style loop.
// Phase 6 : write clipped [300,4], zero-padded.

#define PRE 2000
#define POST 300
#define TILE 512
#define IOU_THR 0.7f
#define EPSV 1e-8f
#define SORTN 2048
#define NBINS 2048
#define CANDCAP 512
#define NT 1024

__device__ __forceinline__ uint32_t flip_f32(uint32_t b) {
    // monotone map: float total order -> unsigned total order
    return b ^ ((uint32_t)((int32_t)b >> 31) | 0x80000000u);
}

__device__ __forceinline__ int bin_of(float s) {
    // monotone (non-injective) bucketing; uniform for U[0,1) scores
    int bn = (int)(s * 2048.0f);
    return min(max(bn, 0), NBINS - 1);
}

__device__ __forceinline__ bool iou_gt(const float4& bi, float ai,
                                       const float4& bj, float aj) {
    // identical op order to reference: inter / (ai + aj - inter + EPS) > thr
    float yy1 = fmaxf(bi.x, bj.x);
    float xx1 = fmaxf(bi.y, bj.y);
    float yy2 = fminf(bi.z, bj.z);
    float xx2 = fminf(bi.w, bj.w);
    float inter = fmaxf(yy2 - yy1, 0.f) * fmaxf(xx2 - xx1, 0.f);
    float iou = inter / (ai + aj - inter + EPSV);
    return iou > IOU_THR;
}

__global__ __launch_bounds__(NT) void roibbox_kernel(
    const float4* __restrict__ deltas,   // [B*N] (dy,dx,dh,dw)
    const float*  __restrict__ labels,   // [B*N]
    const float4* __restrict__ anchors,  // [N]   (y1,x1,y2,x2)
    float4*       __restrict__ out,      // [B*POST]
    int N)
{
    const int b   = blockIdx.x;
    const int tid = threadIdx.x;

    __shared__ union SU {
        uint32_t hist[NBINS];                            // phases 1-1b
        struct { float4 box[PRE]; float area[PRE]; } s;  // phases 4+
    } u;
    __shared__ union PU {
        uint64_t pairs[SORTN];           // phases 2-4: (bits<<32) | ~idx
        uint32_t supmat[TILE][16];       // phases 5a-5b: suppression tile
    } p;
    __shared__ uint64_t cand[CANDCAP];   // selected-bin candidates
    __shared__ uint32_t mask[63];        // fallback suppression mask
    __shared__ uint32_t kept[POST];
    __shared__ int sh_bsel, sh_tprime, sh_cnt, sh_nc, sh_kc;
    __shared__ uint32_t sh_pivot;

    const float*  score  = labels + (size_t)b * N;
    const float4* score4 = (const float4*)score;   // N%4==0, 16B aligned
    const int N4 = N >> 2;

    // ---- Phase 1: uniform-bin histogram ----
    for (int i = tid; i < NBINS; i += NT) u.hist[i] = 0u;
    if (tid == 0) { sh_cnt = 0; sh_nc = 0; }
    __syncthreads();
    for (int n = tid; n < N4; n += NT) {
        float4 v = score4[n];
        atomicAdd(&u.hist[bin_of(v.x)], 1u);
        atomicAdd(&u.hist[bin_of(v.y)], 1u);
        atomicAdd(&u.hist[bin_of(v.z)], 1u);
        atomicAdd(&u.hist[bin_of(v.w)], 1u);
    }
    __syncthreads();

    // ---- Phase 1b: suffix scan; hist[i] becomes S(i)=#{bin >= i} ----
    for (int off = 1; off < NBINS; off <<= 1) {
        uint32_t v0 = (tid + off        < NBINS) ? u.hist[tid + off]        : 0u;
        uint32_t v1 = (tid + 1024 + off < NBINS) ? u.hist[tid + 1024 + off] : 0u;
        __syncthreads();
        u.hist[tid]        += v0;
        u.hist[tid + 1024] += v1;
        __syncthreads();
    }
#pragma unroll
    for (int h = 0; h < 2; ++h) {
        int i = tid + h * 1024;
        uint32_t Si    = u.hist[i];
        uint32_t Snext = (i < NBINS - 1) ? u.hist[i + 1] : 0u;
        if (Si >= (uint32_t)PRE && Snext < (uint32_t)PRE) {
            sh_bsel   = i;                 // largest bin with S(bin) >= PRE
            sh_tprime = PRE - (int)Snext;  // rank still needed inside bin
        }
    }
    __syncthreads();
    const int bsel   = sh_bsel;
    const int tprime = sh_tprime;

    // ---- Phase 2: gather scan ----
    for (int n = tid; n < N4; n += NT) {
        float4 v = score4[n];
        float sv[4] = {v.x, v.y, v.z, v.w};
#pragma unroll
        for (int c = 0; c < 4; ++c) {
            int idx = 4 * n + c;
            int bn  = bin_of(sv[c]);
            if (bn >= bsel) {
                uint32_t ub  = flip_f32(__float_as_uint(sv[c]));
                uint64_t key = ((uint64_t)ub << 32) | (uint32_t)(~(uint32_t)idx);
                if (bn > bsel) {
                    int q = atomicAdd(&sh_cnt, 1);   // total = S(bsel+1) < PRE
                    p.pairs[q] = key;
                } else {
                    int t = atomicAdd(&sh_nc, 1);
                    if (t < CANDCAP) cand[t] = key;
                }
            }
        }
    }
    __syncthreads();

    // ---- Phase 2b: exact pivot among candidates ----
    const int nc = min(sh_nc, CANDCAP);
    for (int i = tid; i < nc; i += NT) {
        uint32_t vi = (uint32_t)(cand[i] >> 32);
        int g = 0, e = 0;
        for (int j = 0; j < nc; ++j) {
            uint32_t vj = (uint32_t)(cand[j] >> 32);
            g += (vj > vi);
            e += (vj == vi);
        }
        if (g < tprime && g + e >= tprime) sh_pivot = vi;  // unique value
    }
    __syncthreads();
    const uint32_t pivot = sh_pivot;
    for (int i = tid; i < nc; i += NT) {
        uint32_t vi = (uint32_t)(cand[i] >> 32);
        if (vi >= pivot) {               // ties included; sort orders by idx
            int q = atomicAdd(&sh_cnt, 1);
            if (q < SORTN) p.pairs[q] = cand[i];
        }
    }
    __syncthreads();
    const int total = min(sh_cnt, SORTN);   // >= PRE by construction
    for (int q = total + tid; q < SORTN; q += NT)
        p.pairs[q] = 0ull;                  // pad sorts below all real keys
    __syncthreads();

    // ---- Phase 3: descending bitonic sort of 2048 u64 keys ----
    for (int k = 2; k <= SORTN; k <<= 1) {
        for (int j = k >> 1; j > 0; j >>= 1) {
            int i = 2 * tid - (tid & (j - 1));
            int l = i | j;
            uint64_t a = p.pairs[i], c = p.pairs[l];
            bool up = ((i & k) == 0);
            bool sw = up ? (a < c) : (a > c);
            if (sw) { p.pairs[i] = c; p.pairs[l] = a; }
            __syncthreads();
        }
    }

    // ---- Phase 4: decode top-2000 boxes into LDS ----
    const float4* dl = deltas + (size_t)b * N;
    for (int r = tid; r < PRE; r += NT) {
        uint32_t idx = ~(uint32_t)(p.pairs[r] & 0xFFFFFFFFull);
        float4 bx = make_float4(0.f, 0.f, 0.f, 0.f);
        float  ar = 0.f;
        if (idx < (uint32_t)N) {
            float4 d  = dl[idx];
            float4 an = anchors[idx];
            float ah  = an.z - an.x;
            float aw  = an.w - an.y;
            float acy = an.x + 0.5f * ah;
            float acx = an.y + 0.5f * aw;
            float h   = expf(d.z) * ah;
            float w   = expf(d.w) * aw;
            float cy  = d.x * ah + acy;
            float cx  = d.y * aw + acx;
            float y1  = cy - 0.5f * h;
            float x1  = cx - 0.5f * w;
            bx = make_float4(y1, x1, y1 + h, x1 + w);
            ar = fmaxf(bx.z - bx.x, 0.f) * fmaxf(bx.w - bx.y, 0.f);
        }
        u.s.box[r]  = bx;
        u.s.area[r] = ar;
    }
    for (int i = tid; i < 63; i += NT) mask[i] = 0u;
    __syncthreads();   // pairs dead from here; supmat may overwrite

    // ---- Phase 5a: 512x512 suppression bitmask tile ----
    // supmat[i][w] bit c = (IoU(box[i], box[w*32+c]) > thr) for j>i, else 0
    for (int idx = tid; idx < TILE * 16; idx += NT) {
        int i = idx >> 4;
        int w = idx & 15;
        int jbase = w << 5;
        uint32_t bits = 0u;
        if (jbase + 31 > i) {
            float4 bi = u.s.box[i];
            float  ai = u.s.area[i];
#pragma unroll
            for (int c = 0; c < 32; ++c) {
                int j = jbase + c;
                if (j > i && iou_gt(bi, ai, u.s.box[j], u.s.area[j]))
                    bits |= (1u << c);
            }
        }
        p.supmat[i][w] = bits;
    }
    __syncthreads();

    // ---- Phase 5b: single-wave sequential reduce (no barriers) ----
    if (tid < 64) {
        const int lane = tid;
        uint32_t supw = 0u;              // lanes 0..15: suppressed-bit word
        int kc = 0, cur = 0;
        while (true) {
            uint32_t avail = (lane < 16) ? ~supw : 0u;
            int base = lane << 5;
            int rel  = cur - base;
            if (rel > 0) avail = (rel >= 32) ? 0u : (avail & (0xFFFFFFFFu << rel));
            int cand_i = avail ? (base + __ffs(avail) - 1) : 0x7FFFFFFF;
#pragma unroll
            for (int off = 32; off; off >>= 1)
                cand_i = min(cand_i, __shfl_xor(cand_i, off, 64));
            if (cand_i >= TILE) break;   // tile exhausted
            if (lane == 0) kept[kc] = (uint32_t)cand_i;
            ++kc;
            if (kc >= POST) break;       // keep flags monotone: final
            if (lane < 16) supw |= p.supmat[cand_i][lane];
            cur = cand_i + 1;
        }
        if (lane == 0) sh_kc = kc;
    }
    __syncthreads();
    int kc = sh_kc;

    // ---- Phase 5c: fallback beyond the tile (not taken on this data) ----
    if (kc < POST) {
        // suppress j in [TILE, PRE) against all kept boxes
        for (int j = TILE + tid; j < PRE; j += NT) {
            float4 bj = u.s.box[j];
            float  aj = u.s.area[j];
            bool sup = false;
            for (int k = 0; k < kc; ++k) {
                int i = (int)kept[k];
                if (iou_gt(u.s.box[i], u.s.area[i], bj, aj)) { sup = true; break; }
            }
            if (sup) atomicOr(&mask[j >> 5], 1u << (j & 31));
        }
        __syncthreads();
        int i = TILE;
        while (i < PRE) {
            while (i < PRE && ((mask[i >> 5] >> (i & 31)) & 1u)) ++i;
            if (i >= PRE) break;
            if (tid == 0) kept[kc] = (uint32_t)i;
            ++kc;
            if (kc >= POST) break;
            float4 bi = u.s.box[i];
            float  ai = u.s.area[i];
            for (int j = i + 1 + tid; j < PRE; j += NT) {
                if (iou_gt(bi, ai, u.s.box[j], u.s.area[j]))
                    atomicOr(&mask[j >> 5], 1u << (j & 31));
            }
            ++i;
            __syncthreads();
        }
    }
    __syncthreads();

    // ---- Phase 6: write clipped output ----
    float4* ob = out + (size_t)b * POST;
    for (int r = tid; r < POST; r += NT) {
        float4 o = make_float4(0.f, 0.f, 0.f, 0.f);
        if (r < kc) {
            float4 bx = u.s.box[kept[r]];
            o.x = fminf(fmaxf(bx.x, 0.f), 1.f);
            o.y = fminf(fmaxf(bx.y, 0.f), 1.f);
            o.z = fminf(fmaxf(bx.z, 0.f), 1.f);
            o.w = fminf(fmaxf(bx.w, 0.f), 1.f);
        }
        ob[r] = o;
    }
}

extern "C" void kernel_launch(void* const* d_in, const int* in_sizes, int n_in,
                              void* d_out, int out_size, void* d_ws, size_t ws_size,
                              hipStream_t stream) {
    const float4* deltas  = (const float4*)d_in[0];
    const float*  labels  = (const float*)d_in[1];
    const float4* anchors = (const float4*)d_in[2];
    float4*       outp    = (float4*)d_out;
    const int N = in_sizes[2] / 4;      // 90000
    const int B = in_sizes[1] / N;      // 64
    roibbox_kernel<<<B, NT, 0, stream>>>(deltas, labels, anchors, outp, N);
}

// Round 4
// 192.420 us; speedup vs baseline: 2.0999x; 1.2634x over previous
//
#include <hip/hip_runtime.h>
#include <stdint.h>

// RPN RoI proposal: per-batch exact top-2000 (lax.top_k order) -> decode ->
// greedy NMS (IoU>0.7) -> first 300 kept, clipped.
//
// One block per batch image, 1024 threads (16 waves).
// Phase 1 : value-uniform 2048-bin histogram (float4 loads, no contention).
// Phase 1b: wave-shuffle suffix scan (1 barrier) -> selected bin + rank.
// Phase 2 : gather scan: bins>bsel -> pairs; bin==bsel -> candidates.
// Phase 2b: exact pivot among <=512 candidates (O(nc^2), exact f32 bits).
// Phase 3 : bitonic sort 2048 u64 keys in REGISTERS (2/lane x 16 waves):
//           j<64 shfl_xor, j==64 in-lane, j>=128 via LDS (10 steps, 20
//           barriers total vs 66) -> exact lax.top_k order.
// Phase 4 : decode boxes into LDS.
// Phase 5a: 512x512 suppression bitmask tile, lanes vary i (broadcast j
//           reads), transposed supmat[16][513] -> conflict-free.
// Phase 5b: single-wave sequential reduce over tile rows (no barriers).
// Phase 5c: fallback (kc<300 after 512 rows; not taken on this data).
// Phase 6 : write clipped [300,4], zero-padded.

#define PRE 2000
#define POST 300
#define TILE 512
#define IOU_THR 0.7f
#define EPSV 1e-8f
#define SORTN 2048
#define NBINS 2048
#define CANDCAP 512
#define NT 1024

__device__ __forceinline__ uint32_t flip_f32(uint32_t b) {
    // monotone map: float total order -> unsigned total order
    return b ^ ((uint32_t)((int32_t)b >> 31) | 0x80000000u);
}

__device__ __forceinline__ int bin_of(float s) {
    // monotone (non-injective) bucketing; uniform for U[0,1) scores
    int bn = (int)(s * 2048.0f);
    return min(max(bn, 0), NBINS - 1);
}

__device__ __forceinline__ bool iou_gt(const float4& bi, float ai,
                                       const float4& bj, float aj) {
    // identical op order to reference: inter / (ai + aj - inter + EPS) > thr
    float yy1 = fmaxf(bi.x, bj.x);
    float xx1 = fmaxf(bi.y, bj.y);
    float yy2 = fminf(bi.z, bj.z);
    float xx2 = fminf(bi.w, bj.w);
    float inter = fmaxf(yy2 - yy1, 0.f) * fmaxf(xx2 - xx1, 0.f);
    float iou = inter / (ai + aj - inter + EPSV);
    return iou > IOU_THR;
}

// bitonic compare-keep: element index i, partner distance j, stage k.
__device__ __forceinline__ unsigned long long cs_keep(
    unsigned long long v, unsigned long long pv, int i, int j, int k) {
    bool lower   = ((i & j) == 0);
    bool desc    = ((i & k) == 0);
    bool keepmax = (desc == lower);
    unsigned long long mx = v > pv ? v : pv;
    unsigned long long mn = v > pv ? pv : v;
    return keepmax ? mx : mn;
}

__global__ __launch_bounds__(NT) void roibbox_kernel(
    const float4* __restrict__ deltas,   // [B*N] (dy,dx,dh,dw)
    const float*  __restrict__ labels,   // [B*N]
    const float4* __restrict__ anchors,  // [N]   (y1,x1,y2,x2)
    float4*       __restrict__ out,      // [B*POST]
    int N)
{
    const int b    = blockIdx.x;
    const int tid  = threadIdx.x;
    const int lane = tid & 63;
    const int wv   = tid >> 6;           // wave id 0..15

    __shared__ union SU {
        uint32_t hist[NBINS];                            // phases 1-1b
        struct { float4 box[PRE]; float area[PRE]; } s;  // phases 4+
    } u;
    __shared__ union PU {
        unsigned long long pairs[SORTN]; // phases 2-4: (bits<<32) | ~idx
        uint32_t supmat[16][TILE + 1];   // phases 5a-5b (513: conflict-free)
    } p;
    __shared__ unsigned long long cand[CANDCAP];
    __shared__ uint32_t mask[63];        // fallback suppression mask
    __shared__ uint32_t kept[POST];
    __shared__ uint32_t wtot[16];        // per-wave histogram totals
    __shared__ int sh_bsel, sh_tprime, sh_cnt, sh_nc, sh_kc;
    __shared__ uint32_t sh_pivot;

    const float*  score  = labels + (size_t)b * N;
    const float4* score4 = (const float4*)score;   // N%4==0, 16B aligned
    const int N4 = N >> 2;

    // ---- Phase 1: uniform-bin histogram ----
    for (int i = tid; i < NBINS; i += NT) u.hist[i] = 0u;
    if (tid == 0) { sh_cnt = 0; sh_nc = 0; }
    __syncthreads();
    for (int n = tid; n < N4; n += NT) {
        float4 v = score4[n];
        atomicAdd(&u.hist[bin_of(v.x)], 1u);
        atomicAdd(&u.hist[bin_of(v.y)], 1u);
        atomicAdd(&u.hist[bin_of(v.z)], 1u);
        atomicAdd(&u.hist[bin_of(v.w)], 1u);
    }
    __syncthreads();

    // ---- Phase 1b: wave-shuffle suffix scan (1 barrier) ----
    // wave wv owns bins [wv*128, wv*128+128): h0 = low half, h1 = high half
    {
        const int i0 = wv * 128 + lane;
        const int i1 = i0 + 64;
        int h0 = (int)u.hist[i0];
        int h1 = (int)u.hist[i1];
        int s0 = h0, s1 = h1;            // inclusive suffix scans per half
#pragma unroll
        for (int off = 1; off < 64; off <<= 1) {
            int t0 = __shfl_down(s0, off, 64);
            int t1 = __shfl_down(s1, off, 64);
            if (lane + off < 64) { s0 += t0; s1 += t1; }
        }
        int sum_h1 = __shfl(s1, 0, 64);  // total of high half
        if (lane == 0) wtot[wv] = (uint32_t)(__shfl(s0, 0, 64) + sum_h1);
        __syncthreads();
        int offtot = 0;
        for (int w2 = wv + 1; w2 < 16; ++w2) offtot += (int)wtot[w2];
        int S0 = s0 + sum_h1 + offtot;   // S(i0) = #{bin >= i0}
        int S1 = s1 + offtot;            // S(i1)
        if (S0 >= PRE && S0 - h0 < PRE) { sh_bsel = i0; sh_tprime = PRE - (S0 - h0); }
        if (S1 >= PRE && S1 - h1 < PRE) { sh_bsel = i1; sh_tprime = PRE - (S1 - h1); }
    }
    __syncthreads();
    const int bsel   = sh_bsel;
    const int tprime = sh_tprime;

    // ---- Phase 2: gather scan ----
    for (int n = tid; n < N4; n += NT) {
        float4 v = score4[n];
        float sv[4] = {v.x, v.y, v.z, v.w};
#pragma unroll
        for (int c = 0; c < 4; ++c) {
            int idx = 4 * n + c;
            int bn  = bin_of(sv[c]);
            if (bn >= bsel) {
                uint32_t ub = flip_f32(__float_as_uint(sv[c]));
                unsigned long long key =
                    ((unsigned long long)ub << 32) | (uint32_t)(~(uint32_t)idx);
                if (bn > bsel) {
                    int q = atomicAdd(&sh_cnt, 1);   // total = S(bsel+1) < PRE
                    p.pairs[q] = key;
                } else {
                    int t = atomicAdd(&sh_nc, 1);
                    if (t < CANDCAP) cand[t] = key;
                }
            }
        }
    }
    __syncthreads();

    // ---- Phase 2b: exact pivot among candidates ----
    const int nc = min(sh_nc, CANDCAP);
    for (int i = tid; i < nc; i += NT) {
        uint32_t vi = (uint32_t)(cand[i] >> 32);
        int g = 0, e = 0;
        for (int j = 0; j < nc; ++j) {
            uint32_t vj = (uint32_t)(cand[j] >> 32);
            g += (vj > vi);
            e += (vj == vi);
        }
        if (g < tprime && g + e >= tprime) sh_pivot = vi;  // unique value
    }
    __syncthreads();
    const uint32_t pivot = sh_pivot;
    for (int i = tid; i < nc; i += NT) {
        uint32_t vi = (uint32_t)(cand[i] >> 32);
        if (vi >= pivot) {               // ties included; sort orders by idx
            int q = atomicAdd(&sh_cnt, 1);
            if (q < SORTN) p.pairs[q] = cand[i];
        }
    }
    __syncthreads();
    const int total = min(sh_cnt, SORTN);   // >= PRE by construction
    for (int q = total + tid; q < SORTN; q += NT)
        p.pairs[q] = 0ull;                  // pad sorts below all real keys
    __syncthreads();

    // ---- Phase 3: bitonic sort in registers (2 elems/lane x 16 waves) ----
    {
        const int i0 = wv * 128 + lane;      // element indices owned
        const int i1 = i0 + 64;
        unsigned long long e0 = p.pairs[i0];
        unsigned long long e1 = p.pairs[i1];
        for (int k = 2; k <= SORTN; k <<= 1) {
            for (int j = k >> 1; j > 0; j >>= 1) {
                if (j >= 128) {              // cross-wave via LDS
                    p.pairs[i0] = e0;
                    p.pairs[i1] = e1;
                    __syncthreads();
                    unsigned long long p0 = p.pairs[i0 ^ j];
                    unsigned long long p1 = p.pairs[i1 ^ j];
                    __syncthreads();
                    e0 = cs_keep(e0, p0, i0, j, k);
                    e1 = cs_keep(e1, p1, i1, j, k);
                } else if (j == 64) {        // partner is own other register
                    unsigned long long a = e0, c = e1;
                    e0 = cs_keep(a, c, i0, 64, k);
                    e1 = cs_keep(c, a, i1, 64, k);
                } else {                     // intra-wave shuffle
                    e0 = cs_keep(e0, __shfl_xor(e0, j, 64), i0, j, k);
                    e1 = cs_keep(e1, __shfl_xor(e1, j, 64), i1, j, k);
                }
            }
        }
        p.pairs[i0] = e0;
        p.pairs[i1] = e1;
    }
    __syncthreads();

    // ---- Phase 4: decode top-2000 boxes into LDS ----
    const float4* dl = deltas + (size_t)b * N;
    for (int r = tid; r < PRE; r += NT) {
        uint32_t idx = ~(uint32_t)(p.pairs[r] & 0xFFFFFFFFull);
        float4 bx = make_float4(0.f, 0.f, 0.f, 0.f);
        float  ar = 0.f;
        if (idx < (uint32_t)N) {
            float4 d  = dl[idx];
            float4 an = anchors[idx];
            float ah  = an.z - an.x;
            float aw  = an.w - an.y;
            float acy = an.x + 0.5f * ah;
            float acx = an.y + 0.5f * aw;
            float h   = expf(d.z) * ah;
            float w   = expf(d.w) * aw;
            float cy  = d.x * ah + acy;
            float cx  = d.y * aw + acx;
            float y1  = cy - 0.5f * h;
            float x1  = cx - 0.5f * w;
            bx = make_float4(y1, x1, y1 + h, x1 + w);
            ar = fmaxf(bx.z - bx.x, 0.f) * fmaxf(bx.w - bx.y, 0.f);
        }
        u.s.box[r]  = bx;
        u.s.area[r] = ar;
    }
    for (int i = tid; i < 63; i += NT) mask[i] = 0u;
    __syncthreads();   // pairs dead from here; supmat may overwrite

    // ---- Phase 5a: 512x512 suppression tile, conflict-free layout ----
    // task (i, w): bits c = IoU(box[i], box[w*32+c]) > thr for j>i.
    // lanes vary i -> box[j] reads are wave-broadcast; store transposed.
    for (int idx = tid; idx < TILE * 16; idx += NT) {
        int i = idx & (TILE - 1);
        int w = idx >> 9;                // 0..15 over 8 grid-stride steps
        int jbase = w << 5;
        float4 bi = u.s.box[i];
        float  ai = u.s.area[i];
        uint32_t bits = 0u;
        if (jbase + 31 > i) {
#pragma unroll
            for (int c = 0; c < 32; ++c) {
                int j = jbase + c;
                if (j > i && iou_gt(bi, ai, u.s.box[j], u.s.area[j]))
                    bits |= (1u << c);
            }
        }
        p.supmat[w][i] = bits;
    }
    __syncthreads();

    // ---- Phase 5b: single-wave sequential reduce (no barriers) ----
    if (tid < 64) {
        uint32_t supw = 0u;              // lanes 0..15: suppressed-bit word
        int kc = 0, cur = 0;
        while (true) {
            uint32_t avail = (lane < 16) ? ~supw : 0u;
            int base = lane << 5;
            int rel  = cur - base;
            if (rel > 0) avail = (rel >= 32) ? 0u : (avail & (0xFFFFFFFFu << rel));
            int cand_i = avail ? (base + __ffs(avail) - 1) : 0x7FFFFFFF;
#pragma unroll
            for (int off = 32; off; off >>= 1)
                cand_i = min(cand_i, __shfl_xor(cand_i, off, 64));
            if (cand_i >= TILE) break;   // tile exhausted
            if (lane == 0) kept[kc] = (uint32_t)cand_i;
            ++kc;
            if (kc >= POST) break;       // keep flags monotone: final
            if (lane < 16) supw |= p.supmat[lane][cand_i];
            cur = cand_i + 1;
        }
        if (lane == 0) sh_kc = kc;
    }
    __syncthreads();
    int kc = sh_kc;

    // ---- Phase 5c: fallback beyond the tile (not taken on this data) ----
    if (kc < POST) {
        for (int j = TILE + tid; j < PRE; j += NT) {
            float4 bj = u.s.box[j];
            float  aj = u.s.area[j];
            bool sup = false;
            for (int k = 0; k < kc; ++k) {
                int i = (int)kept[k];
                if (iou_gt(u.s.box[i], u.s.area[i], bj, aj)) { sup = true; break; }
            }
            if (sup) atomicOr(&mask[j >> 5], 1u << (j & 31));
        }
        __syncthreads();
        int i = TILE;
        while (i < PRE) {
            while (i < PRE && ((mask[i >> 5] >> (i & 31)) & 1u)) ++i;
            if (i >= PRE) break;
            if (tid == 0) kept[kc] = (uint32_t)i;
            ++kc;
            if (kc >= POST) break;
            float4 bi = u.s.box[i];
            float  ai = u.s.area[i];
            for (int j = i + 1 + tid; j < PRE; j += NT) {
                if (iou_gt(bi, ai, u.s.box[j], u.s.area[j]))
                    atomicOr(&mask[j >> 5], 1u << (j & 31));
            }
            ++i;
            __syncthreads();
        }
    }
    __syncthreads();

    // ---- Phase 6: write clipped output ----
    float4* ob = out + (size_t)b * POST;
    for (int r = tid; r < POST; r += NT) {
        float4 o = make_float4(0.f, 0.f, 0.f, 0.f);
        if (r < kc) {
            float4 bx = u.s.box[kept[r]];
            o.x = fminf(fmaxf(bx.x, 0.f), 1.f);
            o.y = fminf(fmaxf(bx.y, 0.f), 1.f);
            o.z = fminf(fmaxf(bx.z, 0.f), 1.f);
            o.w = fminf(fmaxf(bx.w, 0.f), 1.f);
        }
        ob[r] = o;
    }
}

extern "C" void kernel_launch(void* const* d_in, const int* in_sizes, int n_in,
                              void* d_out, int out_size, void* d_ws, size_t ws_size,
                              hipStream_t stream) {
    const float4* deltas  = (const float4*)d_in[0];
    const float*  labels  = (const float*)d_in[1];
    const float4* anchors = (const float4*)d_in[2];
    float4*       outp    = (float4*)d_out;
    const int N = in_sizes[2] / 4;      // 90000
    const int B = in_sizes[1] / N;      // 64
    roibbox_kernel<<<B, NT, 0, stream>>>(deltas, labels, anchors, outp, N);
}